// Round 11
// baseline (131.194 us; speedup 1.0000x reference)
//
#include <hip/hip_runtime.h>

typedef __attribute__((ext_vector_type(8))) short bf16x8;
typedef __attribute__((ext_vector_type(4))) float f32x4;
typedef __attribute__((ext_vector_type(4))) unsigned int u32x4;

static __device__ __forceinline__ unsigned short f2bf_rne(float f) {
    union { float f; unsigned int i; } c; c.f = f;
    unsigned int u = c.i;
    return (unsigned short)((u + 0x7fffu + ((u >> 16) & 1u)) >> 16);
}
static __device__ __forceinline__ unsigned int fbits(float f) {
    union { float f; unsigned int i; } c; c.f = f; return c.i;
}
static __device__ __forceinline__ unsigned int pack_bf16_rne(float lo, float hi) {
    unsigned int ul = fbits(lo), uh = fbits(hi);
    unsigned int tl = ul + 0x7fffu + ((ul >> 16) & 1u);
    unsigned int th = uh + 0x7fffu + ((uh >> 16) & 1u);
    return __builtin_amdgcn_perm(th, tl, 0x07060302u);
}

struct Frags {
    bf16x8 w1h0, w1h1, w2h;
    f32x4 b1v, b2v;
};

// GEMM1: A = W1^T (bf16 RNE). W1 k-row order: [own | x-1 | x+1 | y-1 | y+1 | z-1 | z+1]
// -> block0 quads {own,x-1,x+1,y-1}, block1 {y+1,z-1,z+1,pad(0)}.
// GEMM2: A2[m=s][k=8q+j] = (j<4) ? W2[4q+j][s] : 0.
static __device__ __forceinline__ void build_frags(
    const float* W1, const float* b1, const float* W2, const float* b2,
    int col, int quad, Frags& F)
{
#pragma unroll
    for (int j = 0; j < 8; ++j) {
        int k0 = quad * 8 + j;
        F.w1h0[j] = (short)f2bf_rne(W1[k0 * 16 + col]);
        int k1 = 32 + quad * 8 + j;
        F.w1h1[j] = (short)f2bf_rne((k1 < 56) ? W1[k1 * 16 + col] : 0.0f);
        float w2 = (j < 4 && col < 8) ? W2[(quad * 4 + j) * 8 + col] : 0.0f;
        F.w2h[j] = (short)f2bf_rne(w2);
    }
#pragma unroll
    for (int r = 0; r < 4; ++r) {
        F.b1v[r] = b1[quad * 4 + r];
        F.b2v[r] = (quad < 2) ? b2[quad * 4 + r] : 0.0f;
    }
}

__global__ __launch_bounds__(64) void setup_kernel(
    const float* __restrict__ W1, const float* __restrict__ b1,
    const float* __restrict__ W2, const float* __restrict__ b2,
    u32x4* __restrict__ ws)
{
    const int lane = threadIdx.x;
    Frags F;
    build_frags(W1, b1, W2, b2, lane & 15, lane >> 4, F);
    union { bf16x8 v; u32x4 u; } c;
    c.v = F.w1h0; ws[0 * 64 + lane] = c.u;
    c.v = F.w1h1; ws[1 * 64 + lane] = c.u;
    c.v = F.w2h;  ws[2 * 64 + lane] = c.u;
    union { f32x4 v; u32x4 u; } b;
    b.v = F.b1v; ws[3 * 64 + lane] = b.u;
    b.v = F.b2v; ws[4 * 64 + lane] = b.u;
}

// BARRIER-FREE direct-global streaming (r11). No LDS, no barriers, no
// phases: each wave continuously interleaves global reads -> pack ->
// MFMA -> NT stores, copy-kernel style. Rationale: r6's ablation ledger
// (M2=10, compute=8.5, stores=2, M1=18.5, F=35 us/gen) is STRICTLY
// ADDITIVE across seven schedules -- the device runs in global phase
// lockstep (all CUs read, then all compute, then all store), so reads
// and writes never co-occupy the memory system. The m13 copy kernel
// (continuous per-wave mixing) sustains 6.3 TB/s where our phase-locked
// kernels plateau at ~3.0 aggregate. This kernel has NOTHING that can
// re-align waves: independent rows per wave, latency jitter decorrelates.
// Cost: f32->bf16 pack per use (~40 VALU/i-iter) -- VALUBusy was 22%,
// 4x headroom. x+-1 neighbor reads hit the same L1 lines as own-row;
// y/z neighbors are served by L2/L3 (344 MB aggregate ~ 10 us).
// Block: 8 y-rows x 1 z (2 rows/wave). 2048 blocks, 256 thr, no LDS.
template<bool USE_WS>
__global__ __launch_bounds__(256, 4) void lattice_kernel(
    const float* __restrict__ states,
    const float* __restrict__ W1, const float* __restrict__ b1,
    const float* __restrict__ W2, const float* __restrict__ b2,
    float* __restrict__ out, const u32x4* __restrict__ ws)
{
    const int tid  = threadIdx.x;
    const int lane = tid & 63;
    const int w    = __builtin_amdgcn_readfirstlane(tid >> 6);   // 0..3, SGPR
    const int col  = lane & 15;
    const int quad = lane >> 4;

    Frags F;
    if (USE_WS) {
        union { u32x4 u; bf16x8 v; } c;
        c.u = ws[0 * 64 + lane]; F.w1h0 = c.v;
        c.u = ws[1 * 64 + lane]; F.w1h1 = c.v;
        c.u = ws[2 * 64 + lane]; F.w2h  = c.v;
        union { u32x4 u; f32x4 v; } b;
        b.u = ws[3 * 64 + lane]; F.b1v = b.v;
        b.u = ws[4 * 64 + lane]; F.b2v = b.v;
    } else {
        build_frags(W1, b1, W2, b2, col, quad, F);
    }

    // XCD swizzle: blockIdx&7 -> 16-z-plane slab (one XCD's L2).
    // Within slab: inr>>4 = local z (plane-banded progression for L2),
    // inr&15 = y-octet.
    const int bI   = blockIdx.x;                 // 0..2047
    const int slab = bI & 7;
    const int inr  = bI >> 3;                    // 0..255
    const int z    = slab * 16 + (inr >> 4);
    const int yo   = (inr & 15) << 3;            // y0 of 8-row octet

    const int dxA = (quad == 1) ? -1 : (quad == 2) ? 1 : 0;
    const int xA0 = col + dxA;                   // -1..16, wrapped per-i

    auto do_row = [&](int y) {
        const int ym = (y + 127) & 127, yp = (y + 1) & 127;
        const int zm = (z + 127) & 127, zp = (z + 1) & 127;
        const float* b_own = states + ((size_t)((z  << 14) + (y  << 7)) << 3);
        const float* b_ym  = states + ((size_t)((z  << 14) + (ym << 7)) << 3);
        const float* b_yp  = states + ((size_t)((z  << 14) + (yp << 7)) << 3);
        const float* b_zm  = states + ((size_t)((zm << 14) + (y  << 7)) << 3);
        const float* b_zp  = states + ((size_t)((zp << 14) + (y  << 7)) << 3);
        // per-lane neighbor base: frag A = {own,x-1,x+1,y-1}, frag B =
        // {y+1,z-1,z+1,dummy(own; w1h1[quad3]==0 so content unused)}
        const float* bA = (quad == 3) ? b_ym : b_own;
        const float* bB = (quad == 0) ? b_yp : (quad == 1) ? b_zm
                        : (quad == 2) ? b_zp : b_own;
        float* pO = out + (size_t)(((z << 14) + (y << 7) + col) * 8 + quad * 4);

        f32x4 accs[8];                           // distinct regs; batch stores
#pragma unroll
        for (int i = 0; i < 8; ++i) {
            const int xA = (xA0 + (i << 4)) & 127;   // x periodic wrap
            const int xB = col + (i << 4);           // never wraps
            const float* pa = bA + ((size_t)xA << 3);
            const float* pb = bB + ((size_t)xB << 3);
            f32x4 a0 = *(const f32x4*)(pa);
            f32x4 a1 = *(const f32x4*)(pa + 4);
            f32x4 c0 = *(const f32x4*)(pb);
            f32x4 c1 = *(const f32x4*)(pb + 4);

            union { bf16x8 v; unsigned int u[4]; } s0, s1;
            s0.u[0] = pack_bf16_rne(a0[0], a0[1]);
            s0.u[1] = pack_bf16_rne(a0[2], a0[3]);
            s0.u[2] = pack_bf16_rne(a1[0], a1[1]);
            s0.u[3] = pack_bf16_rne(a1[2], a1[3]);
            s1.u[0] = pack_bf16_rne(c0[0], c0[1]);
            s1.u[1] = pack_bf16_rne(c0[2], c0[3]);
            s1.u[2] = pack_bf16_rne(c1[0], c1[1]);
            s1.u[3] = pack_bf16_rne(c1[2], c1[3]);

            // GEMM1: D1[hidden][cell], bias in C
            f32x4 acc = F.b1v;
            acc = __builtin_amdgcn_mfma_f32_16x16x32_bf16(F.w1h0, s0.v, acc, 0, 0, 0);
            acc = __builtin_amdgcn_mfma_f32_16x16x32_bf16(F.w1h1, s1.v, acc, 0, 0, 0);

            // tanh
            float h0t, h1t, h2t, h3t;
            {
                float e;
                e = __expf(2.0f * acc[0]); h0t = 1.0f - 2.0f * __builtin_amdgcn_rcpf(e + 1.0f);
                e = __expf(2.0f * acc[1]); h1t = 1.0f - 2.0f * __builtin_amdgcn_rcpf(e + 1.0f);
                e = __expf(2.0f * acc[2]); h2t = 1.0f - 2.0f * __builtin_amdgcn_rcpf(e + 1.0f);
                e = __expf(2.0f * acc[3]); h3t = 1.0f - 2.0f * __builtin_amdgcn_rcpf(e + 1.0f);
            }
            union { bf16x8 v; unsigned int u[4]; } hf;
            hf.u[0] = pack_bf16_rne(h0t, h1t);
            hf.u[1] = pack_bf16_rne(h2t, h3t);
            hf.u[2] = 0u;
            hf.u[3] = 0u;

            // GEMM2: D2[s][cell], bias in C
            f32x4 a2 = F.b2v;
            a2 = __builtin_amdgcn_mfma_f32_16x16x32_bf16(F.w2h, hf.v, a2, 0, 0, 0);
            accs[i] = a2;
        }
        if (quad < 2) {
#pragma unroll
            for (int i = 0; i < 8; ++i) {
                __builtin_nontemporal_store(accs[i], (f32x4*)(pO + (i << 7)));
            }
        }
    };

    do_row(yo + w);
    do_row(yo + w + 4);
}

extern "C" void kernel_launch(void* const* d_in, const int* in_sizes, int n_in,
                              void* d_out, int out_size, void* d_ws, size_t ws_size,
                              hipStream_t stream) {
    const float* states = (const float*)d_in[0];
    const float* W1     = (const float*)d_in[1];
    const float* b1     = (const float*)d_in[2];
    const float* W2     = (const float*)d_in[3];
    const float* b2     = (const float*)d_in[4];
    float* out          = (float*)d_out;

    const bool use_ws = ws_size >= (size_t)(5 * 64 * 16);
    if (use_ws) {
        hipLaunchKernelGGL(setup_kernel, dim3(1), dim3(64), 0, stream,
                           W1, b1, W2, b2, (u32x4*)d_ws);
        hipLaunchKernelGGL((lattice_kernel<true>), dim3(2048), dim3(256), 0, stream,
                           states, W1, b1, W2, b2, out, (const u32x4*)d_ws);
    } else {
        hipLaunchKernelGGL((lattice_kernel<false>), dim3(2048), dim3(256), 0, stream,
                           states, W1, b1, W2, b2, out, (const u32x4*)d_ws);
    }
}

// Round 12
// 119.730 us; speedup vs baseline: 1.0957x; 1.0957x over previous
//
#include <hip/hip_runtime.h>

#define SLOT_STRIDE 2096                    // 131*16: 130 halo cells + pad
#define PLANE_STRIDE (6 * SLOT_STRIDE)      // 6 y-rows (y0-1 .. y0+4) per z-plane buffer

typedef __attribute__((ext_vector_type(8))) short bf16x8;
typedef __attribute__((ext_vector_type(4))) float f32x4;
typedef __attribute__((ext_vector_type(4))) unsigned int u32x4;

static __device__ __forceinline__ unsigned short f2bf_rne(float f) {
    union { float f; unsigned int i; } c; c.f = f;
    unsigned int u = c.i;
    return (unsigned short)((u + 0x7fffu + ((u >> 16) & 1u)) >> 16);
}
static __device__ __forceinline__ unsigned int fbits(float f) {
    union { float f; unsigned int i; } c; c.f = f; return c.i;
}
static __device__ __forceinline__ unsigned int pack_bf16_rne(float lo, float hi) {
    unsigned int ul = fbits(lo), uh = fbits(hi);
    unsigned int tl = ul + 0x7fffu + ((ul >> 16) & 1u);
    unsigned int th = uh + 0x7fffu + ((uh >> 16) & 1u);
    return __builtin_amdgcn_perm(th, tl, 0x07060302u);
}

// LDS-only barrier: ds_write -> ds_read ordering without __syncthreads()'s
// vmcnt(0) drain. Producer loads / consumer NT stores stay in flight.
static __device__ __forceinline__ void barrier_lds_only() {
    asm volatile("s_waitcnt lgkmcnt(0)" ::: "memory");
    __builtin_amdgcn_s_barrier();
    __builtin_amdgcn_sched_barrier(0);
}

struct Frags {
    bf16x8 w1h0, w1h1, w2h;
    f32x4 b1v, b2v;
};

// GEMM1: A = W1^T (bf16 RNE). W1 k-row order: [own | x-1 | x+1 | y-1 | y+1 | z-1 | z+1]
// GEMM2: A2[m=s][k=8q+j] = (j<4) ? W2[4q+j][s] : 0.
static __device__ __forceinline__ void build_frags(
    const float* W1, const float* b1, const float* W2, const float* b2,
    int col, int quad, Frags& F)
{
#pragma unroll
    for (int j = 0; j < 8; ++j) {
        int k0 = quad * 8 + j;
        F.w1h0[j] = (short)f2bf_rne(W1[k0 * 16 + col]);
        int k1 = 32 + quad * 8 + j;
        F.w1h1[j] = (short)f2bf_rne((k1 < 56) ? W1[k1 * 16 + col] : 0.0f);
        float w2 = (j < 4 && col < 8) ? W2[(quad * 4 + j) * 8 + col] : 0.0f;
        F.w2h[j] = (short)f2bf_rne(w2);
    }
#pragma unroll
    for (int r = 0; r < 4; ++r) {
        F.b1v[r] = b1[quad * 4 + r];
        F.b2v[r] = (quad < 2) ? b2[quad * 4 + r] : 0.0f;
    }
}

__global__ __launch_bounds__(64) void setup_kernel(
    const float* __restrict__ W1, const float* __restrict__ b1,
    const float* __restrict__ W2, const float* __restrict__ b2,
    u32x4* __restrict__ ws)
{
    const int lane = threadIdx.x;
    Frags F;
    build_frags(W1, b1, W2, b2, lane & 15, lane >> 4, F);
    union { bf16x8 v; u32x4 u; } c;
    c.v = F.w1h0; ws[0 * 64 + lane] = c.u;
    c.v = F.w1h1; ws[1 * 64 + lane] = c.u;
    c.v = F.w2h;  ws[2 * 64 + lane] = c.u;
    union { f32x4 v; u32x4 u; } b;
    b.v = F.b1v; ws[3 * 64 + lane] = b.u;
    b.v = F.b2v; ws[4 * 64 + lane] = b.u;
}

// BEST-MEASURED VARIANT (r9, total 121.27us) -- restored byte-identical.
// Producer/consumer wave specialization, z-marching z0..z0+7, 512 blocks.
// Waves 0-3 (consumers): ds_read -> MFMA -> tanh -> MFMA; NT stores batched
//   at END of step from 8 DISTINCT register sets (no store-WAR waits).
// Waves 4-5 (producers): global loads + bf16-pack + ds_write; vmcnt queue
//   holds only loads, waited one full step after issue.
// 4 rotating plane buffers; producer writes buf (s+3)%4 while consumers
// read (s, s+1, s+2)%4 -- disjoint every step; one LDS-only barrier/step.
// Session ledger: 8 structural variants (buffer count, barrier semantics,
// prefetch depth, z-extent, barrier count 9/1/0, wave roles, store path,
// store reg discipline, LDS vs direct-global) all plateau at kernel
// ~33-37us vs ~21us HBM floor; components strictly additive. This is the
// empirical plateau for this mixed NT-write/strided-read pattern.
template<bool USE_WS>
__global__ __launch_bounds__(384, 3) void lattice_kernel(
    const float* __restrict__ states,
    const float* __restrict__ W1, const float* __restrict__ b1,
    const float* __restrict__ W2, const float* __restrict__ b2,
    float* __restrict__ out, const u32x4* __restrict__ ws)
{
    __shared__ __align__(16) unsigned char lds[4 * PLANE_STRIDE];   // 50304 B

    const int tid  = threadIdx.x;
    const int lane = tid & 63;
    const int w    = __builtin_amdgcn_readfirstlane(tid >> 6);   // 0..5, SGPR
    const int col  = lane & 15;
    const int quad = lane >> 4;

    // XCD swizzle: blockIdx&7 -> 16-z-plane slab; inr>>5 = z half; inr&31 = y0/4.
    const int bI   = blockIdx.x;
    const int slab = bI & 7;
    const int inr  = bI >> 3;                    // 0..63
    const int z0   = slab * 16 + ((inr >> 5) << 3);
    const int y0   = (inr & 31) << 2;

    if (w >= 4) {
        // ---------------- producer waves (w = 4,5) ----------------
        const int wp = w - 4;                    // 0/1: tasks wp*6 .. wp*6+5

        f32x4 Pa[6], Pb[6], Qa[6], Qb[6];

        auto issueP = [&](int zp, f32x4* a, f32x4* b) {
#pragma unroll
            for (int i = 0; i < 6; ++i) {
                const int tk   = wp * 6 + i;     // SALU geometry
                const int r    = tk >> 1;
                const int half = tk & 1;
                const int yr   = (y0 - 1 + r) & 127;
                const float* g = states +
                    ((size_t)((((unsigned)(zp & 127)) << 14) + (yr << 7) + (half << 6)) << 3);
                a[i] = *(const f32x4*)(g + (lane << 3));
                b[i] = *(const f32x4*)(g + (lane << 3) + 4);
            }
        };
        auto writeP = [&](int buf, const f32x4* a, const f32x4* b) {
#pragma unroll
            for (int i = 0; i < 6; ++i) {
                const int tk   = wp * 6 + i;
                const int r    = tk >> 1;
                const int half = tk & 1;
                u32x4 p;
                p[0] = __builtin_amdgcn_perm(fbits(a[i][1]), fbits(a[i][0]), 0x07060302u);
                p[1] = __builtin_amdgcn_perm(fbits(a[i][3]), fbits(a[i][2]), 0x07060302u);
                p[2] = __builtin_amdgcn_perm(fbits(b[i][1]), fbits(b[i][0]), 0x07060302u);
                p[3] = __builtin_amdgcn_perm(fbits(b[i][3]), fbits(b[i][2]), 0x07060302u);
                unsigned char* base = lds + buf * PLANE_STRIDE + r * SLOT_STRIDE;
                *(u32x4*)(base + ((half * 64 + lane + 1) << 4)) = p;
                // halo: cell 128 <- x=0 (half0 lane0); cell -1 <- x=127 (half1 lane63)
                if (half == 0 && lane == 0)  *(u32x4*)(base + 2064) = p;
                if (half == 1 && lane == 63) *(u32x4*)(base) = p;
            }
        };

        // prologue: planes z0-1, z0, z0+1 -> bufs 0..2; z0+2 left pending in Q
        issueP(z0 - 1, Pa, Pb);
        issueP(z0,     Qa, Qb);
        writeP(0, Pa, Pb);
        issueP(z0 + 1, Pa, Pb);
        writeP(1, Qa, Qb);
        issueP(z0 + 2, Qa, Qb);
        writeP(2, Pa, Pb);
        barrier_lds_only();                              // B0

        // steady: write plane (loaded one step ago), issue next; barrier
        writeP(3, Qa, Qb); issueP(z0 + 3, Qa, Qb); barrier_lds_only();  // s=0: z0+2
        writeP(0, Qa, Qb); issueP(z0 + 4, Qa, Qb); barrier_lds_only();  // s=1: z0+3
        writeP(1, Qa, Qb); issueP(z0 + 5, Qa, Qb); barrier_lds_only();  // s=2: z0+4
        writeP(2, Qa, Qb); issueP(z0 + 6, Qa, Qb); barrier_lds_only();  // s=3: z0+5
        writeP(3, Qa, Qb); issueP(z0 + 7, Qa, Qb); barrier_lds_only();  // s=4: z0+6
        writeP(0, Qa, Qb); issueP(z0 + 8, Qa, Qb); barrier_lds_only();  // s=5: z0+7
        writeP(1, Qa, Qb);                         barrier_lds_only();  // s=6: z0+8
        // s=7: nothing; no trailing barrier on either role
    } else {
        // ---------------- consumer waves (w = 0..3) ----------------
        Frags F;
        if (USE_WS) {
            union { u32x4 u; bf16x8 v; } c;
            c.u = ws[0 * 64 + lane]; F.w1h0 = c.v;
            c.u = ws[1 * 64 + lane]; F.w1h1 = c.v;
            c.u = ws[2 * 64 + lane]; F.w2h  = c.v;
            union { u32x4 u; f32x4 v; } b;
            b.u = ws[3 * 64 + lane]; F.b1v = b.v;
            b.u = ws[4 * 64 + lane]; F.b2v = b.v;
        } else {
            build_frags(W1, b1, W2, b2, col, quad, F);
        }

        const int dxA  = (quad == 1) ? -1 : (quad == 2) ? 1 : 0;
        const int rA   = (quad == 3) ? w : w + 1;        // {own,x+-1}: own row; y-1: row w
        const int rB   = (quad == 0) ? w + 2 : w + 1;    // y+1: row w+2; z+-1/pad: own row
        const int offA = rA * SLOT_STRIDE + ((col + dxA + 1) << 4);
        const int offB = rB * SLOT_STRIDE + ((col + 1) << 4);

        auto compute_step = [&](int zc, int bufZm, int bufZ, int bufZp) {
            const unsigned char* pA = lds + bufZ * PLANE_STRIDE + offA;
            const int bB = (quad == 1) ? bufZm : (quad == 2) ? bufZp : bufZ;
            const unsigned char* pB = lds + bB * PLANE_STRIDE + offB;
            float* pO = out + (size_t)(((zc << 14) + ((y0 + w) << 7) + col) * 8 + quad * 4);

            // Phase 1: compute 8 results into 8 DISTINCT register sets
            // (static indices only -- rule 20). No stores in this phase.
            f32x4 accs[8];
#pragma unroll
            for (int i = 0; i < 8; ++i) {
                bf16x8 s0f = *(const bf16x8*)(pA + (i << 8));
                bf16x8 s1f = *(const bf16x8*)(pB + (i << 8));

                // GEMM1: D1[hidden][cell], bias in C
                f32x4 acc = F.b1v;
                acc = __builtin_amdgcn_mfma_f32_16x16x32_bf16(F.w1h0, s0f, acc, 0, 0, 0);
                acc = __builtin_amdgcn_mfma_f32_16x16x32_bf16(F.w1h1, s1f, acc, 0, 0, 0);

                // tanh
                float h0t, h1t, h2t, h3t;
                {
                    float e;
                    e = __expf(2.0f * acc[0]); h0t = 1.0f - 2.0f * __builtin_amdgcn_rcpf(e + 1.0f);
                    e = __expf(2.0f * acc[1]); h1t = 1.0f - 2.0f * __builtin_amdgcn_rcpf(e + 1.0f);
                    e = __expf(2.0f * acc[2]); h2t = 1.0f - 2.0f * __builtin_amdgcn_rcpf(e + 1.0f);
                    e = __expf(2.0f * acc[3]); h3t = 1.0f - 2.0f * __builtin_amdgcn_rcpf(e + 1.0f);
                }
                union { bf16x8 v; unsigned int u[4]; } hf;
                hf.u[0] = pack_bf16_rne(h0t, h1t);
                hf.u[1] = pack_bf16_rne(h2t, h3t);
                hf.u[2] = 0u;
                hf.u[3] = 0u;

                // GEMM2: D2[s][cell], bias in C -> own register set
                f32x4 a2 = F.b2v;
                a2 = __builtin_amdgcn_mfma_f32_16x16x32_bf16(F.w2h, hf.v, a2, 0, 0, 0);
                accs[i] = a2;
            }

            // Phase 2: batched NT stores from distinct regs. Their source
            // VGPRs are not rewritten until NEXT step's phase 1 (~us later),
            // so the store-WAR vmcnt waits are fully covered.
            if (quad < 2) {
#pragma unroll
                for (int i = 0; i < 8; ++i) {
                    __builtin_nontemporal_store(accs[i], (f32x4*)(pO + (i << 7)));
                }
            }
        };

        barrier_lds_only();                              // match producer B0
        compute_step(z0 + 0, 0, 1, 2); barrier_lds_only();
        compute_step(z0 + 1, 1, 2, 3); barrier_lds_only();
        compute_step(z0 + 2, 2, 3, 0); barrier_lds_only();
        compute_step(z0 + 3, 3, 0, 1); barrier_lds_only();
        compute_step(z0 + 4, 0, 1, 2); barrier_lds_only();
        compute_step(z0 + 5, 1, 2, 3); barrier_lds_only();
        compute_step(z0 + 6, 2, 3, 0); barrier_lds_only();
        compute_step(z0 + 7, 3, 0, 1);                   // no trailing barrier
    }
}

extern "C" void kernel_launch(void* const* d_in, const int* in_sizes, int n_in,
                              void* d_out, int out_size, void* d_ws, size_t ws_size,
                              hipStream_t stream) {
    const float* states = (const float*)d_in[0];
    const float* W1     = (const float*)d_in[1];
    const float* b1     = (const float*)d_in[2];
    const float* W2     = (const float*)d_in[3];
    const float* b2     = (const float*)d_in[4];
    float* out          = (float*)d_out;

    const bool use_ws = ws_size >= (size_t)(5 * 64 * 16);
    if (use_ws) {
        hipLaunchKernelGGL(setup_kernel, dim3(1), dim3(64), 0, stream,
                           W1, b1, W2, b2, (u32x4*)d_ws);
        hipLaunchKernelGGL((lattice_kernel<true>), dim3(512), dim3(384), 0, stream,
                           states, W1, b1, W2, b2, out, (const u32x4*)d_ws);
    } else {
        hipLaunchKernelGGL((lattice_kernel<false>), dim3(512), dim3(384), 0, stream,
                           states, W1, b1, W2, b2, out, (const u32x4*)d_ws);
    }
}